// Round 3
// baseline (121.610 us; speedup 1.0000x reference)
//
#include <hip/hip_runtime.h>
#include <stdint.h>

#pragma clang fp contract(off)

typedef __attribute__((ext_vector_type(4))) int i32x4;
typedef __attribute__((ext_vector_type(16))) int i32x16;

#define B_    16
#define C_    128
#define HW_   56
#define L_    3136      // 56*56
#define CO_   128
#define F_    1152      // 128*9
#define M_    50176     // 16*3136

// ---- workspace layout (bytes) ----
#define OFF_SW   256        // float scale_w[128]
#define OFF_ZPW  768        // int   zp_w[128]
#define OFF_CT   1280       // int   const_term[128]
#define OFF_QW   4096       // int8  qw[j][o][c] = 9*128*128 = 147456
#define OFF_QX   153600     // int8  qx_t[b][l][c] = 6422528 (channel-last)
#define OFF_S    6576128    // int   S[b][3136] channel-sums = 200704
#define OFF_SQ   6776832    // int   sum_qx[50176] = 200704
#define OFF_RES  6977536    // int   res[50176][128] = 25690112 (end ~32.7MB)

struct QP { unsigned xmin_enc, xmax_enc; int rmin, rmax; };

__device__ __forceinline__ unsigned enc_f(float f) {
    unsigned u = __float_as_uint(f);
    return (u & 0x80000000u) ? ~u : (u | 0x80000000u);
}
__device__ __forceinline__ float dec_f(unsigned e) {
    return __uint_as_float((e & 0x80000000u) ? (e ^ 0x80000000u) : ~e);
}
__device__ __forceinline__ int read_abit(const int* p) {
    int i = *p;
    if (i > 0 && i < 32) return i;
    float f = __int_as_float(i);
    int fi = (int)f;
    return (fi > 0 && fi < 32) ? fi : 8;
}
__device__ __forceinline__ void get_sx(const QP* P, int abit, float& sx, float& zx) {
    float xmin = dec_f(P->xmin_enc), xmax = dec_f(P->xmax_enc);
    float n = (float)((1 << abit) - 1);
    sx = n / fmaxf(xmax - xmin, 1e-8f);
    zx = rintf(sx * xmin) + (float)(1 << (abit - 1));
}

// ---------------- kernels ----------------

__global__ void k_init(char* ws) {
    if (threadIdx.x == 0) {
        QP* P = (QP*)ws;
        P->xmin_enc = 0x80000000u;  // enc(0.0f): padding zeros count
        P->xmax_enc = 0x80000000u;
        P->rmin = INT32_MAX;
        P->rmax = INT32_MIN;
    }
}

__global__ void k_xminmax(const float4* __restrict__ x4, int n4, char* ws) {
    QP* P = (QP*)ws;
    float mn = 0.0f, mx = 0.0f;
    int stride = gridDim.x * blockDim.x;
    for (int i = blockIdx.x * blockDim.x + threadIdx.x; i < n4; i += stride) {
        float4 v = x4[i];
        mn = fminf(mn, fminf(fminf(v.x, v.y), fminf(v.z, v.w)));
        mx = fmaxf(mx, fmaxf(fmaxf(v.x, v.y), fmaxf(v.z, v.w)));
    }
    for (int m = 32; m; m >>= 1) {
        mn = fminf(mn, __shfl_xor(mn, m));
        mx = fmaxf(mx, __shfl_xor(mx, m));
    }
    __shared__ float smn[4], smx[4];
    int w = threadIdx.x >> 6;
    if ((threadIdx.x & 63) == 0) { smn[w] = mn; smx[w] = mx; }
    __syncthreads();
    if (threadIdx.x == 0) {
        mn = fminf(fminf(smn[0], smn[1]), fminf(smn[2], smn[3]));
        mx = fmaxf(fmaxf(smx[0], smx[1]), fmaxf(smx[2], smx[3]));
        atomicMin(&P->xmin_enc, enc_f(mn));
        atomicMax(&P->xmax_enc, enc_f(mx));
    }
}

// one wave per output channel; packs qw as [j][o][c]
__global__ void k_wquant(const float* __restrict__ w, const float* __restrict__ bias,
                         const int* __restrict__ abit_p, char* ws) {
    QP* P = (QP*)ws;
    float* scale_w = (float*)(ws + OFF_SW);
    int* zpw = (int*)(ws + OFF_ZPW);
    int* ct  = (int*)(ws + OFF_CT);
    signed char* qw = (signed char*)(ws + OFF_QW);

    int o = blockIdx.x, lane = threadIdx.x;
    const float* wr = w + o * F_;
    float mn = 3.4e38f, mx = -3.4e38f;
    for (int f = lane; f < F_; f += 64) {
        float v = wr[f];
        mn = fminf(mn, v); mx = fmaxf(mx, v);
    }
    for (int m = 32; m; m >>= 1) {
        mn = fminf(mn, __shfl_xor(mn, m));
        mx = fmaxf(mx, __shfl_xor(mx, m));
    }
    float sw = 255.0f / fmaxf(mx - mn, 1e-8f);
    float zw = rintf(sw * mn) + 128.0f;

    int qsum = 0;
    for (int f = lane; f < F_; f += 64) {
        float q = fminf(fmaxf(rintf(sw * wr[f] - zw), -128.0f), 127.0f);
        int qi = (int)q;
        qsum += qi;
        int c = f / 9, j = f - c * 9;
        qw[(j * CO_ + o) * C_ + c] = (signed char)qi;
    }
    for (int m = 32; m; m >>= 1) qsum += __shfl_xor(qsum, m);
    if (lane == 0) {
        int abit = read_abit(abit_p);
        float sx, zx; get_sx(P, abit, sx, zx);
        float qb = rintf(sw * sx * bias[o]);
        int zwi = (int)zw, zxi = (int)zx;
        ct[o] = zxi * qsum + F_ * zwi * zxi + (int)qb;
        zpw[o] = zwi;
        scale_w[o] = sw;
    }
}

// quantize to channel-last qx_t[b][l][c] + per-pixel channel sums S[b][l]
__global__ __launch_bounds__(256) void k_xquant(const float* __restrict__ x,
                                                const int* __restrict__ abit_p, char* ws) {
    __shared__ int ssum[4][64];
    QP* P = (QP*)ws;
    int abit = read_abit(abit_p);
    float sx, zx; get_sx(P, abit, sx, zx);
    int nx = 1 << (abit - 1);
    float lo = -(float)nx, hif = (float)(nx - 1);
    signed char* qxt = (signed char*)(ws + OFF_QX);
    int gid = blockIdx.x;
    int b = gid / 49, lcq = gid - b * 49;
    int l0 = lcq * 64;
    int t = threadIdx.x;
    int lane = t & 63, cg = t >> 6;
    int l = l0 + lane;
    const float* xb = x + ((size_t)b * C_) * L_ + l;
    int4* dst = (int4*)(qxt + ((size_t)(b * L_ + l)) * 128);
    int psum = 0;
    #pragma unroll
    for (int ii = 0; ii < 2; ++ii) {
        int c16 = (cg + 4 * ii) * 16;
        int wds[4];
        #pragma unroll
        for (int k = 0; k < 4; ++k) {
            int wv = 0;
            #pragma unroll
            for (int e = 0; e < 4; ++e) {
                int c = c16 + 4 * k + e;
                float v = xb[(size_t)c * L_];
                int qi = (int)fminf(fmaxf(rintf(sx * v - zx), lo), hif);
                psum += qi;
                wv |= (qi & 255) << (8 * e);
            }
            wds[k] = wv;
        }
        int4 vv; vv.x = wds[0]; vv.y = wds[1]; vv.z = wds[2]; vv.w = wds[3];
        dst[c16 >> 4] = vv;
    }
    ssum[cg][lane] = psum;
    __syncthreads();
    if (cg == 0) {
        int* S = (int*)(ws + OFF_S);
        S[b * L_ + l] = ssum[0][lane] + ssum[1][lane] + ssum[2][lane] + ssum[3][lane];
    }
}

// sum_qx[m] = 3x3 box over S with 128*q0 padding
__global__ void k_boxsum(const int* __restrict__ abit_p, char* ws) {
    QP* P = (QP*)ws;
    const int* S = (const int*)(ws + OFF_S);
    int* sq = (int*)(ws + OFF_SQ);
    int abit = read_abit(abit_p);
    float sx, zx; get_sx(P, abit, sx, zx);
    int nx = 1 << (abit - 1);
    int q0 = min(max(-(int)zx, -nx), nx - 1);
    int pad = C_ * q0;
    int m = blockIdx.x * blockDim.x + threadIdx.x;
    int b = m / L_, l = m - b * L_;
    int oh = l / HW_, ow = l - oh * HW_;
    const int* Sb = S + b * L_;
    int s = 0;
    for (int kh = 0; kh < 3; ++kh) {
        int ih = oh - 1 + kh;
        for (int kw = 0; kw < 3; ++kw) {
            int iw = ow - 1 + kw;
            s += (ih >= 0 && ih < HW_ && iw >= 0 && iw < HW_) ? Sb[ih * HW_ + iw] : pad;
        }
    }
    sq[m] = s;
}

// 64M x 128N MFMA int8 GEMM. A: 4-row x 58-col x 128-ch halo staged ONCE in LDS
// (q0 pad splat, XOR-swizzled 16B chunks); B: direct 16B global loads from
// L2-resident qw[j][o][c]. K-loop has no barriers.
__global__ __launch_bounds__(256) void k_gemm(const int* __restrict__ abit_p, char* __restrict__ ws) {
    __shared__ __align__(16) signed char NB[4 * 58 * 128];   // 29696 B
    __shared__ int red[8];

    QP* P = (QP*)ws;
    const signed char* qxt = (const signed char*)(ws + OFF_QX);
    const signed char* qw  = (const signed char*)(ws + OFF_QW);
    const int* sumqx = (const int*)(ws + OFF_SQ);
    const int* zpw   = (const int*)(ws + OFF_ZPW);
    const int* ct    = (const int*)(ws + OFF_CT);
    int* res = (int*)(ws + OFF_RES);

    int t = threadIdx.x;
    int mg = blockIdx.x * 64;
    int b = mg / L_, l0 = mg - b * L_;
    int prow0 = l0 / HW_;              // 64-row tile spans pixel rows prow0, prow0+1

    int abit = read_abit(abit_p);
    float sx, zx; get_sx(P, abit, sx, zx);
    int nx = 1 << (abit - 1);
    int q0 = min(max(-(int)zx, -nx), nx - 1);
    int pw = (q0 & 255) * 0x01010101;
    int4 pad4; pad4.x = pw; pad4.y = pw; pad4.z = pw; pad4.w = pw;

    const signed char* qxtb = qxt + (size_t)b * L_ * 128;

    // ---- stage halo: rows prow0-1..prow0+2, cols -1..56, swizzle ch ^= pix&7 ----
    #pragma unroll
    for (int i = 0; i < 8; ++i) {
        int slot = t + i * 256;
        if (slot < 1856) {                      // 232 pix * 8 chunks
            int pix = slot >> 3, ch = slot & 7;
            int ri = pix / 58, c1 = pix - ri * 58;
            int ih = prow0 - 1 + ri, iw = c1 - 1;
            int4 v = pad4;
            if ((unsigned)ih < HW_ && (unsigned)iw < HW_)
                v = *(const int4*)(qxtb + ((ih * HW_ + iw) << 7) + (ch << 4));
            *(int4*)&NB[(pix << 7) + ((ch ^ (pix & 7)) << 4)] = v;
        }
    }
    __syncthreads();

    int lane = t & 63, w = t >> 6;
    int wm = (w >> 1) * 32, wn = (w & 1) * 64;
    int r = lane & 31, hi = lane >> 5;

    // per-lane A pixel base inside the halo
    int l = l0 + wm + r;
    int oh = l / HW_, ow = l - oh * HW_;
    int pbase = (oh - prow0 + 1) * 58 + (ow + 1);   // center pixel index in halo

    i32x16 acc0, acc1;
    #pragma unroll
    for (int i = 0; i < 16; ++i) { acc0[i] = 0; acc1[i] = 0; }

    #pragma unroll
    for (int j = 0; j < 9; ++j) {
        int kh = j / 3, kw = j - kh * 3;
        int pix = pbase + (kh - 1) * 58 + (kw - 1);
        const signed char* bj = qw + ((j * CO_) << 7);
        #pragma unroll
        for (int kk = 0; kk < 4; ++kk) {
            int ch = kk * 2 + hi;                // 16B chunk index = k/16
            i32x4 af = *(const i32x4*)&NB[(pix << 7) + ((ch ^ (pix & 7)) << 4)];
            i32x4 bf0 = *(const i32x4*)(bj + ((wn + r) << 7) + (ch << 4));
            i32x4 bf1 = *(const i32x4*)(bj + ((wn + 32 + r) << 7) + (ch << 4));
            acc0 = __builtin_amdgcn_mfma_i32_32x32x32_i8(af, bf0, acc0, 0, 0, 0);
            acc1 = __builtin_amdgcn_mfma_i32_32x32x32_i8(af, bf1, acc1, 0, 0, 0);
        }
    }

    // epilogue: zero-point corrections, res write, global min/max
    int o0 = wn + r, o1 = wn + 32 + r;
    int zw0 = zpw[o0], c0 = ct[o0];
    int zw1 = zpw[o1], c1 = ct[o1];
    int lmin = INT32_MAX, lmax = INT32_MIN;
    #pragma unroll
    for (int g = 0; g < 16; ++g) {
        int row = (g & 3) + ((g >> 2) << 3) + (hi << 2);
        int m = mg + wm + row;
        int s = sumqx[m];
        int v0 = acc0[g] + zw0 * s + c0;
        int v1 = acc1[g] + zw1 * s + c1;
        lmin = min(lmin, min(v0, v1));
        lmax = max(lmax, max(v0, v1));
        res[m * CO_ + o0] = v0;
        res[m * CO_ + o1] = v1;
    }
    for (int m = 32; m; m >>= 1) {
        lmin = min(lmin, __shfl_xor(lmin, m));
        lmax = max(lmax, __shfl_xor(lmax, m));
    }
    if ((t & 63) == 0) { red[t >> 6] = lmin; red[4 + (t >> 6)] = lmax; }
    __syncthreads();
    if (t == 0) {
        lmin = min(min(red[0], red[1]), min(red[2], red[3]));
        lmax = max(max(red[4], red[5]), max(red[6], red[7]));
        atomicMin(&P->rmin, lmin);
        atomicMax(&P->rmax, lmax);
    }
}

// requantize + dequantize with LDS tile transpose; out [B][Cout][L]
__global__ __launch_bounds__(256) void k_deq(const int* __restrict__ abit_p, char* ws,
                                             float* __restrict__ out) {
    __shared__ int tile[64 * 65];
    QP* P = (QP*)ws;
    const int* res = (const int*)(ws + OFF_RES);
    const float* scale_w = (const float*)(ws + OFF_SW);
    int t = threadIdx.x;
    int bid = blockIdx.x;
    int lcq = bid % 49; int tmp2 = bid / 49; int ocq = tmp2 & 1; int b = tmp2 >> 1;
    int l0 = lcq * 64, o0 = ocq * 64;

    const int* resb = res + ((size_t)(b * L_ + l0)) * CO_ + o0;
    #pragma unroll
    for (int i = 0; i < 4; ++i) {
        int lr = (t >> 4) + i * 16;
        int oc4 = (t & 15) * 4;
        int4 v = *(const int4*)(resb + lr * CO_ + oc4);
        int* d = &tile[lr * 65 + oc4];
        d[0] = v.x; d[1] = v.y; d[2] = v.z; d[3] = v.w;
    }

    int abit = read_abit(abit_p);
    float sxv, zxv; get_sx(P, abit, sxv, zxv);
    int nxq = 1 << (abit - 1);
    float nlev = (float)((1 << abit) - 1);
    float rmin = (float)P->rmin, rmax = (float)P->rmax;
    float sr = nlev / fmaxf(rmax - rmin, 1e-8f);
    float zr = rintf(sr * rmin) + (float)nxq;
    float lo = -(float)nxq, hiq = (float)(nxq - 1);

    __syncthreads();

    #pragma unroll
    for (int i = 0; i < 4; ++i) {
        int o = (t >> 4) + i * 16;
        int l4 = (t & 15) * 4;
        float swsx = scale_w[o0 + o] * sxv;
        float4 f;
        #pragma unroll
        for (int jj = 0; jj < 4; ++jj) {
            int rv = tile[(l4 + jj) * 65 + o];
            float q = fminf(fmaxf(rintf(sr * (float)rv - zr), lo), hiq);
            ((float*)&f)[jj] = ((q + zr) / sr) / swsx;
        }
        *(float4*)(out + ((size_t)(b * CO_ + o0 + o)) * L_ + l0 + l4) = f;
    }
}

// ---------------- launch ----------------

extern "C" void kernel_launch(void* const* d_in, const int* in_sizes, int n_in,
                              void* d_out, int out_size, void* d_ws, size_t ws_size,
                              hipStream_t stream) {
    const float* x      = (const float*)d_in[0];
    const float* weight = (const float*)d_in[1];
    const float* bias   = (const float*)d_in[2];
    const int*   abit   = (const int*)d_in[3];
    float* out = (float*)d_out;
    char* ws = (char*)d_ws;

    int n4 = (B_ * C_ * L_) / 4;

    k_init<<<1, 64, 0, stream>>>(ws);
    k_xminmax<<<1024, 256, 0, stream>>>((const float4*)x, n4, ws);
    k_wquant<<<128, 64, 0, stream>>>(weight, bias, abit, ws);
    k_xquant<<<784, 256, 0, stream>>>(x, abit, ws);
    k_boxsum<<<M_ / 256, 256, 0, stream>>>(abit, ws);
    k_gemm<<<M_ / 64, 256, 0, stream>>>(abit, ws);
    k_deq<<<1568, 256, 0, stream>>>(abit, ws, out);
}

// Round 4
// 103.553 us; speedup vs baseline: 1.1744x; 1.1744x over previous
//
#include <hip/hip_runtime.h>
#include <stdint.h>

#pragma clang fp contract(off)

typedef __attribute__((ext_vector_type(4))) int i32x4;
typedef __attribute__((ext_vector_type(16))) int i32x16;

#define B_    16
#define C_    128
#define HW_   56
#define L_    3136      // 56*56
#define CO_   128
#define F_    1152      // 128*9
#define M_    50176     // 16*3136

// ---- workspace layout (bytes) ----
#define OFF_SW   256        // float scale_w[128]
#define OFF_ZPW  768        // int   zp_w[128]
#define OFF_CT   1280       // int   const_term[128]
#define OFF_QW   4096       // int8  qw2[j][ch][o][16] = 9*8*128*16 = 147456
#define OFF_QX   153600     // int8  qx_t[b][l][c] = 6422528 (channel-last)
#define OFF_S    6576128    // int   S[b][3136] channel-sums = 200704 (end ~6.8MB)

struct QP { unsigned xmin_enc, xmax_enc; int rmin, rmax; };

__device__ __forceinline__ unsigned enc_f(float f) {
    unsigned u = __float_as_uint(f);
    return (u & 0x80000000u) ? ~u : (u | 0x80000000u);
}
__device__ __forceinline__ float dec_f(unsigned e) {
    return __uint_as_float((e & 0x80000000u) ? (e ^ 0x80000000u) : ~e);
}
__device__ __forceinline__ int read_abit(const int* p) {
    int i = *p;
    if (i > 0 && i < 32) return i;
    float f = __int_as_float(i);
    int fi = (int)f;
    return (fi > 0 && fi < 32) ? fi : 8;
}
__device__ __forceinline__ void get_sx(const QP* P, int abit, float& sx, float& zx) {
    float xmin = dec_f(P->xmin_enc), xmax = dec_f(P->xmax_enc);
    float n = (float)((1 << abit) - 1);
    sx = n / fmaxf(xmax - xmin, 1e-8f);
    zx = rintf(sx * xmin) + (float)(1 << (abit - 1));
}

// ---------------- kernels ----------------

__global__ void k_init(char* ws) {
    if (threadIdx.x == 0) {
        QP* P = (QP*)ws;
        P->xmin_enc = 0x80000000u;  // enc(0.0f): padding zeros count
        P->xmax_enc = 0x80000000u;
        P->rmin = INT32_MAX;
        P->rmax = INT32_MIN;
    }
}

__global__ void k_xminmax(const float4* __restrict__ x4, int n4, char* ws) {
    QP* P = (QP*)ws;
    float mn = 0.0f, mx = 0.0f;
    int stride = gridDim.x * blockDim.x;
    for (int i = blockIdx.x * blockDim.x + threadIdx.x; i < n4; i += stride) {
        float4 v = x4[i];
        mn = fminf(mn, fminf(fminf(v.x, v.y), fminf(v.z, v.w)));
        mx = fmaxf(mx, fmaxf(fmaxf(v.x, v.y), fmaxf(v.z, v.w)));
    }
    for (int m = 32; m; m >>= 1) {
        mn = fminf(mn, __shfl_xor(mn, m));
        mx = fmaxf(mx, __shfl_xor(mx, m));
    }
    __shared__ float smn[4], smx[4];
    int w = threadIdx.x >> 6;
    if ((threadIdx.x & 63) == 0) { smn[w] = mn; smx[w] = mx; }
    __syncthreads();
    if (threadIdx.x == 0) {
        mn = fminf(fminf(smn[0], smn[1]), fminf(smn[2], smn[3]));
        mx = fmaxf(fmaxf(smx[0], smx[1]), fmaxf(smx[2], smx[3]));
        atomicMin(&P->xmin_enc, enc_f(mn));
        atomicMax(&P->xmax_enc, enc_f(mx));
    }
}

// one wave per output channel; packs qw2[j][ch][o][16]  (ch = c>>4, byte = c&15)
__global__ void k_wquant(const float* __restrict__ w, const float* __restrict__ bias,
                         const int* __restrict__ abit_p, char* ws) {
    QP* P = (QP*)ws;
    float* scale_w = (float*)(ws + OFF_SW);
    int* zpw = (int*)(ws + OFF_ZPW);
    int* ct  = (int*)(ws + OFF_CT);
    signed char* qw = (signed char*)(ws + OFF_QW);

    int o = blockIdx.x, lane = threadIdx.x;
    const float* wr = w + o * F_;
    float mn = 3.4e38f, mx = -3.4e38f;
    for (int f = lane; f < F_; f += 64) {
        float v = wr[f];
        mn = fminf(mn, v); mx = fmaxf(mx, v);
    }
    for (int m = 32; m; m >>= 1) {
        mn = fminf(mn, __shfl_xor(mn, m));
        mx = fmaxf(mx, __shfl_xor(mx, m));
    }
    float sw = 255.0f / fmaxf(mx - mn, 1e-8f);
    float zw = rintf(sw * mn) + 128.0f;

    int qsum = 0;
    for (int f = lane; f < F_; f += 64) {
        float q = fminf(fmaxf(rintf(sw * wr[f] - zw), -128.0f), 127.0f);
        int qi = (int)q;
        qsum += qi;
        int c = f / 9, j = f - c * 9;
        qw[j * 16384 + (c >> 4) * 2048 + (o << 4) + (c & 15)] = (signed char)qi;
    }
    for (int m = 32; m; m >>= 1) qsum += __shfl_xor(qsum, m);
    if (lane == 0) {
        int abit = read_abit(abit_p);
        float sx, zx; get_sx(P, abit, sx, zx);
        float qb = rintf(sw * sx * bias[o]);
        int zwi = (int)zw, zxi = (int)zx;
        ct[o] = zxi * qsum + F_ * zwi * zxi + (int)qb;
        zpw[o] = zwi;
        scale_w[o] = sw;
    }
}

// quantize to channel-last qx_t[b][l][c] + per-pixel channel sums S[b][l]
__global__ __launch_bounds__(256) void k_xquant(const float* __restrict__ x,
                                                const int* __restrict__ abit_p, char* ws) {
    __shared__ int ssum[4][64];
    QP* P = (QP*)ws;
    int abit = read_abit(abit_p);
    float sx, zx; get_sx(P, abit, sx, zx);
    int nx = 1 << (abit - 1);
    float lo = -(float)nx, hif = (float)(nx - 1);
    signed char* qxt = (signed char*)(ws + OFF_QX);
    int gid = blockIdx.x;
    int b = gid / 49, lcq = gid - b * 49;
    int l0 = lcq * 64;
    int t = threadIdx.x;
    int lane = t & 63, cg = t >> 6;
    int l = l0 + lane;
    const float* xb = x + ((size_t)b * C_) * L_ + l;
    int4* dst = (int4*)(qxt + ((size_t)(b * L_ + l)) * 128);
    int psum = 0;
    #pragma unroll
    for (int ii = 0; ii < 2; ++ii) {
        int c16 = (cg + 4 * ii) * 16;
        int wds[4];
        #pragma unroll
        for (int k = 0; k < 4; ++k) {
            int wv = 0;
            #pragma unroll
            for (int e = 0; e < 4; ++e) {
                int c = c16 + 4 * k + e;
                float v = xb[(size_t)c * L_];
                int qi = (int)fminf(fmaxf(rintf(sx * v - zx), lo), hif);
                psum += qi;
                wv |= (qi & 255) << (8 * e);
            }
            wds[k] = wv;
        }
        int4 vv; vv.x = wds[0]; vv.y = wds[1]; vv.z = wds[2]; vv.w = wds[3];
        dst[c16 >> 4] = vv;
    }
    ssum[cg][lane] = psum;
    __syncthreads();
    if (cg == 0) {
        int* S = (int*)(ws + OFF_S);
        S[b * L_ + l] = ssum[0][lane] + ssum[1][lane] + ssum[2][lane] + ssum[3][lane];
    }
}

// 64M x 128N MFMA int8 GEMM. A: 4x58x128 halo staged once in LDS (XOR swizzle);
// B: coalesced 16B-contiguous-per-lane loads from L2-resident qw2[j][ch][o][16],
// double-buffered in registers. No K-loop barriers.
// PASS 1: global res min/max only. PASS 2: fused requant+dequant, LDS transpose,
// coalesced out write.
#define LOAD_TAP(J, AF, B0, B1) do {                                                    \
    const int pixJ = pbase + ((J) / 3 - 1) * 58 + ((J) % 3 - 1);                        \
    const signed char* bjp = qw + (J) * 16384;                                          \
    _Pragma("unroll")                                                                   \
    for (int kk = 0; kk < 4; ++kk) {                                                    \
        int ch = kk * 2 + hi;                                                           \
        AF[kk] = *(const i32x4*)&NB[(pixJ << 7) + ((ch ^ (pixJ & 7)) << 4)];            \
        B0[kk] = *(const i32x4*)(bjp + ch * 2048 + ((wn + r) << 4));                    \
        B1[kk] = *(const i32x4*)(bjp + ch * 2048 + ((wn + 32 + r) << 4));               \
    }                                                                                   \
} while (0)

template <int PASS>
__global__ __launch_bounds__(256, 3) void k_gemm(const int* __restrict__ abit_p,
                                                 char* __restrict__ ws,
                                                 float* __restrict__ out) {
    __shared__ __align__(16) char pool[(PASS == 2) ? 33024 : 29696];  // NB / f32 tile
    __shared__ int S_s[232];
    __shared__ int sq_s[64];
    __shared__ int red[8];

    QP* P = (QP*)ws;
    const signed char* qxt = (const signed char*)(ws + OFF_QX);
    const signed char* qw  = (const signed char*)(ws + OFF_QW);
    const int* Sg    = (const int*)(ws + OFF_S);
    const int* zpw   = (const int*)(ws + OFF_ZPW);
    const int* ct    = (const int*)(ws + OFF_CT);
    const float* scale_w = (const float*)(ws + OFF_SW);
    signed char* NB = (signed char*)pool;

    int t = threadIdx.x;
    int mg = blockIdx.x * 64;
    int b = mg / L_, l0 = mg - b * L_;
    int prow0 = l0 / HW_;              // tile spans pixel rows prow0, prow0+1

    int abit = read_abit(abit_p);
    float sx, zx; get_sx(P, abit, sx, zx);
    int nx = 1 << (abit - 1);
    int q0 = min(max(-(int)zx, -nx), nx - 1);
    int pw = (q0 & 255) * 0x01010101;
    int4 pad4; pad4.x = pw; pad4.y = pw; pad4.z = pw; pad4.w = pw;
    int padS = C_ * q0;

    const signed char* qxtb = qxt + (size_t)b * L_ * 128;
    const int* Sb = Sg + b * L_;

    // ---- stage halo qx (rows prow0-1..prow0+2, cols -1..56), swizzle ch ^= pix&7 ----
    #pragma unroll
    for (int i = 0; i < 8; ++i) {
        int slot = t + i * 256;
        if (slot < 1856) {                      // 232 pix * 8 chunks
            int pix = slot >> 3, ch = slot & 7;
            int ri = pix / 58, c1 = pix - ri * 58;
            int ih = prow0 - 1 + ri, iw = c1 - 1;
            int4 v = pad4;
            if ((unsigned)ih < HW_ && (unsigned)iw < HW_)
                v = *(const int4*)(qxtb + ((ih * HW_ + iw) << 7) + (ch << 4));
            *(int4*)&NB[(pix << 7) + ((ch ^ (pix & 7)) << 4)] = v;
        }
    }
    // ---- stage halo S ----
    if (t < 232) {
        int ri = t / 58, c1 = t - ri * 58;
        int ih = prow0 - 1 + ri, iw = c1 - 1;
        S_s[t] = ((unsigned)ih < HW_ && (unsigned)iw < HW_) ? Sb[ih * HW_ + iw] : padS;
    }
    __syncthreads();
    // ---- per-row 3x3 box sums (replaces k_boxsum) ----
    if (t < 64) {
        int l = l0 + t;
        int oh = l / HW_, ow = l - oh * HW_;
        int ri = oh - prow0 + 1, ci = ow + 1;
        int s = 0;
        #pragma unroll
        for (int dr = -1; dr <= 1; ++dr)
            #pragma unroll
            for (int dc = -1; dc <= 1; ++dc)
                s += S_s[(ri + dr) * 58 + ci + dc];
        sq_s[t] = s;
    }

    int lane = t & 63, w = t >> 6;
    int wm = (w >> 1) * 32, wn = (w & 1) * 64;
    int r = lane & 31, hi = lane >> 5;

    int l = l0 + wm + r;
    int oh = l / HW_, ow = l - oh * HW_;
    int pbase = (oh - prow0 + 1) * 58 + (ow + 1);

    i32x16 acc0, acc1;
    #pragma unroll
    for (int i = 0; i < 16; ++i) { acc0[i] = 0; acc1[i] = 0; }

    // ---- K-loop: 9 taps, double-buffered fragments, no barriers ----
    i32x4 afc[4], b0c[4], b1c[4], afn[4], b0n[4], b1n[4];
    LOAD_TAP(0, afc, b0c, b1c);
    #pragma unroll
    for (int j = 0; j < 9; ++j) {
        if (j < 8) LOAD_TAP(j + 1, afn, b0n, b1n);
        #pragma unroll
        for (int kk = 0; kk < 4; ++kk) {
            acc0 = __builtin_amdgcn_mfma_i32_32x32x32_i8(afc[kk], b0c[kk], acc0, 0, 0, 0);
            acc1 = __builtin_amdgcn_mfma_i32_32x32x32_i8(afc[kk], b1c[kk], acc1, 0, 0, 0);
        }
        #pragma unroll
        for (int kk = 0; kk < 4; ++kk) { afc[kk] = afn[kk]; b0c[kk] = b0n[kk]; b1c[kk] = b1n[kk]; }
    }

    __syncthreads();   // sq_s ready; (PASS 2) NB free for reuse

    int o0 = wn + r, o1 = wn + 32 + r;
    int zw0 = zpw[o0], c0 = ct[o0];
    int zw1 = zpw[o1], c1 = ct[o1];

    if (PASS == 1) {
        int lmin = INT32_MAX, lmax = INT32_MIN;
        #pragma unroll
        for (int g = 0; g < 16; ++g) {
            int row = (g & 3) + ((g >> 2) << 3) + (hi << 2);
            int s = sq_s[wm + row];
            int v0 = acc0[g] + zw0 * s + c0;
            int v1 = acc1[g] + zw1 * s + c1;
            lmin = min(lmin, min(v0, v1));
            lmax = max(lmax, max(v0, v1));
        }
        for (int m = 32; m; m >>= 1) {
            lmin = min(lmin, __shfl_xor(lmin, m));
            lmax = max(lmax, __shfl_xor(lmax, m));
        }
        if ((t & 63) == 0) { red[t >> 6] = lmin; red[4 + (t >> 6)] = lmax; }
        __syncthreads();
        if (t == 0) {
            lmin = min(min(red[0], red[1]), min(red[2], red[3]));
            lmax = max(max(red[4], red[5]), max(red[6], red[7]));
            atomicMin(&P->rmin, lmin);
            atomicMax(&P->rmax, lmax);
        }
    } else {
        // requantize + dequantize in-register, transpose via LDS, coalesced out
        float nlev = (float)((1 << abit) - 1);
        float rminf = (float)P->rmin, rmaxf = (float)P->rmax;
        float sr = nlev / fmaxf(rmaxf - rminf, 1e-8f);
        float zr = rintf(sr * rminf) + (float)nx;
        float lof = -(float)nx, hiq = (float)(nx - 1);
        float swsx0 = scale_w[o0] * sx;
        float swsx1 = scale_w[o1] * sx;
        float* tile = (float*)pool;            // [64][129]
        #pragma unroll
        for (int g = 0; g < 16; ++g) {
            int row = (g & 3) + ((g >> 2) << 3) + (hi << 2);
            int s = sq_s[wm + row];
            int v0 = acc0[g] + zw0 * s + c0;
            int v1 = acc1[g] + zw1 * s + c1;
            float q0f = fminf(fmaxf(rintf(sr * (float)v0 - zr), lof), hiq);
            float q1f = fminf(fmaxf(rintf(sr * (float)v1 - zr), lof), hiq);
            tile[(wm + row) * 129 + o0] = ((q0f + zr) / sr) / swsx0;
            tile[(wm + row) * 129 + o1] = ((q1f + zr) / sr) / swsx1;
        }
        __syncthreads();
        #pragma unroll
        for (int i = 0; i < 8; ++i) {
            int o = (t >> 4) + i * 16;
            int l4 = (t & 15) * 4;
            float4 f;
            #pragma unroll
            for (int jj = 0; jj < 4; ++jj)
                ((float*)&f)[jj] = tile[(l4 + jj) * 129 + o];
            *(float4*)(out + ((size_t)(b * CO_ + o)) * L_ + l0 + l4) = f;
        }
    }
}

// ---------------- launch ----------------

extern "C" void kernel_launch(void* const* d_in, const int* in_sizes, int n_in,
                              void* d_out, int out_size, void* d_ws, size_t ws_size,
                              hipStream_t stream) {
    const float* x      = (const float*)d_in[0];
    const float* weight = (const float*)d_in[1];
    const float* bias   = (const float*)d_in[2];
    const int*   abit   = (const int*)d_in[3];
    float* out = (float*)d_out;
    char* ws = (char*)d_ws;

    int n4 = (B_ * C_ * L_) / 4;

    k_init<<<1, 64, 0, stream>>>(ws);
    k_xminmax<<<1024, 256, 0, stream>>>((const float4*)x, n4, ws);
    k_wquant<<<128, 64, 0, stream>>>(weight, bias, abit, ws);
    k_xquant<<<784, 256, 0, stream>>>(x, abit, ws);
    k_gemm<1><<<M_ / 64, 256, 0, stream>>>(abit, ws, nullptr);
    k_gemm<2><<<M_ / 64, 256, 0, stream>>>(abit, ws, out);
}